// Round 2
// baseline (324.201 us; speedup 1.0000x reference)
//
#include <hip/hip_runtime.h>

#define T_STEPS 512
#define HSTR 80        // _Float16 per h batch-row (160 B)
#define XSTRIDE 520    // _Float16 per x-row
#define OSTRIDE 513    // floats per out-row
#define NB 8           // batches per block (2 groups x 4), 256 blocks = 1/CU

typedef _Float16 half8v __attribute__((ext_vector_type(8)));
typedef _Float16 half4v __attribute__((ext_vector_type(4)));
typedef float f32x4 __attribute__((ext_vector_type(4)));

#define K1 1.442695041f    // log2(e)
#define K2 2.885390082f    // 2*log2(e)

__device__ __forceinline__ float ex2(float x) {
#if __has_builtin(__builtin_amdgcn_exp2f)
    return __builtin_amdgcn_exp2f(x);
#else
    return exp2f(x);
#endif
}
__device__ __forceinline__ float rcp_fast(float x) {
#if __has_builtin(__builtin_amdgcn_rcpf)
    return __builtin_amdgcn_rcpf(x);
#else
    return 1.0f / x;
#endif
}

// fused LSTM cell activation; args prescaled by -log2e (i,f,o) / 2log2e (g)
__device__ __forceinline__ float lstm_act(float v0, float v1, float v2, float v3,
                                          float& cs) {
    float A  = ex2(v0);                   // e^{-i}
    float Bt = ex2(v2);                   // e^{2g}
    float ig = (Bt - 1.0f) * rcp_fast((1.0f + A) * (1.0f + Bt));
    float rf = rcp_fast(1.0f + ex2(v1));  // sig(f)
    cs = fmaf(cs, rf, ig);
    float cc = fminf(fmaxf(cs, -15.f), 15.f);
    float Ao = ex2(v3);                   // e^{-o}
    float C  = ex2(cc * K2);              // e^{2c}
    return (C - 1.0f) * rcp_fast((1.0f + Ao) * (1.0f + C));
}

// partial fc-dot over this lane's A-frag slice (f16), reduced over the 4 k-quads
__device__ __forceinline__ float out_dot(half8v a0, half8v a1,
                                         const float* wfc0, const float* wfc1) {
    float s = 0.f;
#pragma unroll
    for (int j = 0; j < 8; ++j) s = fmaf((float)a0[j], wfc0[j], s);
#pragma unroll
    for (int j = 0; j < 8; ++j) s = fmaf((float)a1[j], wfc1[j], s);
    s += __shfl_xor(s, 16);
    s += __shfl_xor(s, 32);
    return s;   // full 64-dot for batch (c>>2), on all lanes
}

// R12: dual-group pipeline. One block/CU, NB=8 as 2 independent groups of 4
// batches; both groups' read->MFMA->act->write sit between the SAME barriers,
// so group B's issue fills group A's latency (and vice versa) in-stream.
// Per group: R11's layout (A rows m -> h[m>>2], act batch = q, wave w owns
// units 16w..16w+15). B-frags/bias/wih/wfc shared across groups.
__global__ __launch_bounds__(256, 1) void lstm_kernel(
    const float* __restrict__ x, const float* __restrict__ w_ih,
    const float* __restrict__ w_hh, const float* __restrict__ b_ih,
    const float* __restrict__ b_hh, const float* __restrict__ w_fc,
    const float* __restrict__ b_fc, float* __restrict__ out)
{
    __shared__ __align__(16) _Float16 hbuf[2][NB * HSTR];   // 2.5 KB
    __shared__ __align__(16) _Float16 xls[NB * XSTRIDE];    // 8.3 KB
    __shared__ __align__(16) float ols[NB * OSTRIDE];       // 16.4 KB

    const int tid  = threadIdx.x;
    const int w    = tid >> 6;        // wave 0..3
    const int lane = tid & 63;
    const int q    = lane >> 4;       // quad (A k-group / D row-group)
    const int c    = lane & 15;       // unit-in-tile / A-row
    const int b0   = blockIdx.x * NB;

    // ---- stage x: global -> LDS (f16), coalesced float4 reads ----
    for (int i = tid; i < NB * 128; i += 256) {      // 8 rows x 128 float4
        int b  = i >> 7;
        int t4 = i & 127;
        float4 v = *(const float4*)(x + (size_t)(b0 + b) * T_STEPS + t4 * 4);
        half4v hv;
        hv[0] = (_Float16)v.x; hv[1] = (_Float16)v.y;
        hv[2] = (_Float16)v.z; hv[3] = (_Float16)v.w;
        *(half4v*)(&xls[b * XSTRIDE + t4 * 4]) = hv;
    }
    // zero both h buffers (h_{-1} = 0): 2*8*80 f16 = 640 dwords
    for (int i = tid; i < 2 * NB * HSTR / 2; i += 256) ((int*)hbuf)[i] = 0;

    // ---- B fragments (prescaled weights): tile n = gate class ----
    // lane (q,c) holds B[k=32kk+8q+jj][col c] = sK[n]*w_hh[g][k], g = 64n+16w+c
    const float sK[4] = { -K1, -K1, K2, -K1 };   // i,f sig; g tanh; o sig
    half8v bfrag[4][2];
    float biasS[4], wihS[4];
#pragma unroll
    for (int n = 0; n < 4; ++n) {
        int g = 64 * n + 16 * w + c;
        biasS[n] = (b_ih[g] + b_hh[g]) * sK[n];
        wihS[n]  = w_ih[g] * sK[n];
#pragma unroll
        for (int kk = 0; kk < 2; ++kk) {
            const float* wp = w_hh + g * 64 + 32 * kk + 8 * q;
            float4 lo  = *(const float4*)(wp);
            float4 hi4 = *(const float4*)(wp + 4);
            half8v f;
            f[0] = (_Float16)(lo.x  * sK[n]); f[1] = (_Float16)(lo.y  * sK[n]);
            f[2] = (_Float16)(lo.z  * sK[n]); f[3] = (_Float16)(lo.w  * sK[n]);
            f[4] = (_Float16)(hi4.x * sK[n]); f[5] = (_Float16)(hi4.y * sK[n]);
            f[6] = (_Float16)(hi4.z * sK[n]); f[7] = (_Float16)(hi4.w * sK[n]);
            bfrag[n][kk] = f;
        }
    }

    // fc weights aligned to this lane's A-frag k-slice
    float wfc0[8], wfc1[8];
#pragma unroll
    for (int j = 0; j < 8; ++j) { wfc0[j] = w_fc[8 * q + j]; wfc1[j] = w_fc[32 + 8 * q + j]; }
    const float bfc = b_fc[0];

    float csA = 0.f, csB = 0.f;   // cell state (batch q / 4+q, unit 16w+c)
    const f32x4 zeroq = {0.f, 0.f, 0.f, 0.f};

    __syncthreads();

    half8v sa0A = {}, sa1A = {}, sa0B = {}, sa1B = {};  // saved frags, fc-dot

    for (int tq = 0; tq < 128; ++tq) {
        // x for this lane's own batch in each group, 4 steps (broadcast reads)
        half4v xhA = *(const half4v*)(&xls[q * XSTRIDE + tq * 4]);
        half4v xhB = *(const half4v*)(&xls[(4 + q) * XSTRIDE + tq * 4]);

#pragma unroll
        for (int dt = 0; dt < 4; ++dt) {
            const int t  = tq * 4 + dt;
            const int rb = t & 1;
            const _Float16* hrd = hbuf[rb];

            // A-frags both groups: row m=c -> batch m>>2 (rows 0-3 / 4-7)
            const _Float16* hpA = hrd + (c >> 2) * HSTR + 8 * q;
            const _Float16* hpB = hrd + (4 + (c >> 2)) * HSTR + 8 * q;
            half8v a0A = *(const half8v*)(hpA);
            half8v a1A = *(const half8v*)(hpA + 32);
            half8v a0B = *(const half8v*)(hpB);
            half8v a1B = *(const half8v*)(hpB + 32);

            if (dt == w) { sa0A = a0A; sa1A = a1A; sa0B = a0B; sa1B = a1B; }

            // scalar x*wih+bias, both groups (off critical path)
            const float xvA = (float)xhA[dt], xvB = (float)xhB[dt];
            float xbA[4], xbB[4];
#pragma unroll
            for (int n = 0; n < 4; ++n) {
                xbA[n] = fmaf(xvA, wihS[n], biasS[n]);
                xbB[n] = fmaf(xvB, wihS[n], biasS[n]);
            }

            // gates: 4 class tiles per group, K=64 via chained MFMA pair
            f32x4 accA[4], accB[4];
#pragma unroll
            for (int n = 0; n < 4; ++n) {
                accA[n] = __builtin_amdgcn_mfma_f32_16x16x32_f16(a1A, bfrag[n][1], zeroq, 0, 0, 0);
                accA[n] = __builtin_amdgcn_mfma_f32_16x16x32_f16(a0A, bfrag[n][0], accA[n], 0, 0, 0);
            }
#pragma unroll
            for (int n = 0; n < 4; ++n) {
                accB[n] = __builtin_amdgcn_mfma_f32_16x16x32_f16(a1B, bfrag[n][1], zeroq, 0, 0, 0);
                accB[n] = __builtin_amdgcn_mfma_f32_16x16x32_f16(a0B, bfrag[n][0], accB[n], 0, 0, 0);
            }

            // rows 4q..4q+3 all = batch q (group-local) -> elem 0, no select
            float vA[4], vB[4];
#pragma unroll
            for (int n = 0; n < 4; ++n) vA[n] = accA[n][0] + xbA[n];
#pragma unroll
            for (int n = 0; n < 4; ++n) vB[n] = accB[n][0] + xbB[n];

            _Float16* hwr = hbuf[rb ^ 1];
            float hA = lstm_act(vA[0], vA[1], vA[2], vA[3], csA);
            hwr[q * HSTR + 16 * w + c] = (_Float16)hA;
            float hB = lstm_act(vB[0], vB[1], vB[2], vB[3], csB);
            hwr[(4 + q) * HSTR + 16 * w + c] = (_Float16)hB;

            __syncthreads();
        }

        // rotated fc-dots: saved frag is A of step st = tq*4+w = h_{st-1}
        {
            int st = tq * 4 + w;
            if (st > 0) {
                float sA = out_dot(sa0A, sa1A, wfc0, wfc1);
                float sB = out_dot(sa0B, sa1B, wfc0, wfc1);
                if (lane < 16 && (lane & 3) == 0) {
                    ols[(lane >> 2) * OSTRIDE + (st - 1)]       = sA + bfc;
                    ols[(4 + (lane >> 2)) * OSTRIDE + (st - 1)] = sB + bfc;
                }
            }
        }
    }

    // final output column: h_511 lives in hbuf[0]
    if (w == 3) {
        const _Float16* hpA = hbuf[0] + (c >> 2) * HSTR + 8 * q;
        const _Float16* hpB = hbuf[0] + (4 + (c >> 2)) * HSTR + 8 * q;
        half8v a0A = *(const half8v*)(hpA);
        half8v a1A = *(const half8v*)(hpA + 32);
        half8v a0B = *(const half8v*)(hpB);
        half8v a1B = *(const half8v*)(hpB + 32);
        float sA = out_dot(a0A, a1A, wfc0, wfc1);
        float sB = out_dot(a0B, a1B, wfc0, wfc1);
        if (lane < 16 && (lane & 3) == 0) {
            ols[(lane >> 2) * OSTRIDE + (T_STEPS - 1)]       = sA + bfc;
            ols[(4 + (lane >> 2)) * OSTRIDE + (T_STEPS - 1)] = sB + bfc;
        }
    }
    __syncthreads();

    // bulk store: LDS out -> global, coalesced
    for (int i = tid; i < NB * T_STEPS; i += 256) {
        int b = i >> 9;
        int t = i & (T_STEPS - 1);
        out[(size_t)(b0 + b) * T_STEPS + t] = ols[b * OSTRIDE + t];
    }
}

extern "C" void kernel_launch(void* const* d_in, const int* in_sizes, int n_in,
                              void* d_out, int out_size, void* d_ws, size_t ws_size,
                              hipStream_t stream) {
    const float* x    = (const float*)d_in[0];
    const float* w_ih = (const float*)d_in[1];
    const float* w_hh = (const float*)d_in[2];
    const float* b_ih = (const float*)d_in[3];
    const float* b_hh = (const float*)d_in[4];
    const float* w_fc = (const float*)d_in[5];
    const float* b_fc = (const float*)d_in[6];
    float* out = (float*)d_out;
    hipLaunchKernelGGL(lstm_kernel, dim3(2048 / NB), dim3(256), 0, stream,
                       x, w_ih, w_hh, b_ih, b_hh, w_fc, b_fc, out);
}